// Round 4
// baseline (277.462 us; speedup 1.0000x reference)
//
#include <hip/hip_runtime.h>
#include <cstdint>
#include <cfloat>
#include <math.h>

#define VCAB 128000
#define NROWS 256
#define NTHREADS 1024
#define NBUCK 8192
#define CAP 1024

__device__ __forceinline__ unsigned mono(float f) {
    unsigned u = __float_as_uint(f);
    return (u & 0x80000000u) ? ~u : (u | 0x80000000u);
}
__device__ __forceinline__ float unmono(unsigned k) {
    return __uint_as_float((k & 0x80000000u) ? (k ^ 0x80000000u) : ~k);
}

__global__ __launch_bounds__(NTHREADS) void sampler_kernel(
    const float* __restrict__ logits,
    const float* __restrict__ gumbel,
    const int* __restrict__ topk_p,
    float* __restrict__ out)
{
    const int row = blockIdx.x;
    const int t = threadIdx.x;
    const size_t base = (size_t)row * VCAB;
    const float4* rowv = reinterpret_cast<const float4*>(logits + base);
    const float FMIN = -FLT_MAX;

    __shared__ unsigned hist[NBUCK];
    __shared__ unsigned chunkSum[NTHREADS];
    __shared__ unsigned sufs[NTHREADS];
    __shared__ unsigned long long ck[CAP];
    __shared__ unsigned candCnt;
    __shared__ unsigned sh_bstar;
    __shared__ float red[16];
    __shared__ float sh_m0, sh_S;

    // ---- init ----
    #pragma unroll
    for (int j = 0; j < NBUCK / NTHREADS; ++j) hist[t + j * NTHREADS] = 0u;
    if (t == 0) { candCnt = 0u; sh_bstar = 0u; }
    __syncthreads();

    // ---- Pass 1: row max + histogram of monotonic keys ----
    float lmax = FMIN;
    for (int i = t; i < VCAB / 4; i += NTHREADS) {
        float4 x = rowv[i];
        float vs[4] = {x.x, x.y, x.z, x.w};
        #pragma unroll
        for (int c = 0; c < 4; ++c) {
            float v = vs[c];
            if (!(fabsf(v) <= FLT_MAX)) v = FMIN;   // sanitize NaN/±inf -> finfo.min
            lmax = fmaxf(lmax, v);
            atomicAdd(&hist[mono(v) >> 19], 1u);
        }
    }
    // block max reduce
    for (int off = 32; off > 0; off >>= 1) lmax = fmaxf(lmax, __shfl_xor(lmax, off, 64));
    if ((t & 63) == 0) red[t >> 6] = lmax;
    __syncthreads();
    if (t < 16) {
        float m = red[t];
        for (int off = 8; off > 0; off >>= 1) m = fmaxf(m, __shfl_xor(m, off, 16));
        if (t == 0) sh_m0 = m;
    }
    __syncthreads();
    const float m0 = sh_m0;

    // ---- find threshold bucket: smallest b* s.t. count(bucket >= b*) >= 64 ----
    unsigned cs = 0;
    #pragma unroll
    for (int j = 0; j < NBUCK / NTHREADS; ++j) cs += hist[t * (NBUCK / NTHREADS) + j];
    chunkSum[t] = cs;
    sufs[t] = cs;
    __syncthreads();
    for (int off = 1; off < NTHREADS; off <<= 1) {
        unsigned add = (t + off < NTHREADS) ? sufs[t + off] : 0u;
        __syncthreads();
        sufs[t] += add;
        __syncthreads();
    }
    {
        unsigned incl = sufs[t];            // count in chunks >= t
        unsigned above = incl - cs;         // count in chunks  > t
        if (incl >= 64u && above < 64u) {   // unique crossing chunk
            unsigned acc = above;
            const int bpc = NBUCK / NTHREADS;
            for (int b = t * bpc + bpc - 1; b >= t * bpc; --b) {
                acc += hist[b];
                if (acc >= 64u) { sh_bstar = (unsigned)b; break; }
            }
        }
    }
    __syncthreads();
    const unsigned bstar = sh_bstar;

    // pad candidate keys (0 sorts last in descending order)
    ck[t] = 0ull;
    __syncthreads();

    // ---- Pass 2: sumexp + candidate collection ----
    float ssum = 0.f;
    for (int i = t; i < VCAB / 4; i += NTHREADS) {
        float4 x = rowv[i];
        float vs[4] = {x.x, x.y, x.z, x.w};
        #pragma unroll
        for (int c = 0; c < 4; ++c) {
            float v = vs[c];
            if (!(fabsf(v) <= FLT_MAX)) v = FMIN;
            ssum += expf(v - m0);
            unsigned k = mono(v);
            if ((k >> 19) >= bstar) {
                unsigned pos = atomicAdd(&candCnt, 1u);
                if (pos < CAP)
                    ck[pos] = ((unsigned long long)k << 32) |
                              (unsigned long long)(~(unsigned)(i * 4 + c));
            }
        }
    }
    for (int off = 32; off > 0; off >>= 1) ssum += __shfl_xor(ssum, off, 64);
    if ((t & 63) == 0) red[t >> 6] = ssum;
    __syncthreads();
    if (t < 16) {
        float s = red[t];
        for (int off = 8; off > 0; off >>= 1) s += __shfl_xor(s, off, 16);
        if (t == 0) sh_S = s;
    }
    __syncthreads();
    const float S = sh_S;

    // ---- bitonic sort of 1024 packed keys, descending ----
    // key = (mono(value) << 32) | ~index  -> value desc, index asc on ties
    for (unsigned k = 2; k <= CAP; k <<= 1) {
        for (unsigned j = k >> 1; j > 0; j >>= 1) {
            __syncthreads();
            unsigned l = (unsigned)t ^ j;
            if (l > (unsigned)t) {
                unsigned long long a = ck[t], b = ck[l];
                bool up = (((unsigned)t & k) == 0u);
                if (up ? (a < b) : (a > b)) { ck[t] = b; ck[l] = a; }
            }
        }
    }
    __syncthreads();

    // ---- epilogue: first wave handles sorted top-64 ----
    if (t < 64) {
        unsigned long long key = ck[t];
        float v = unmono((unsigned)(key >> 32));
        int idx = (int)(~(unsigned)key);
        int K = *topk_p;
        K = min(max(K, 1), 64);

        // exclusive cumulative softmax prob over sorted order (full-row S)
        float p = expf(v - m0) / S;
        float pref = p;
        for (int off = 1; off < 64; off <<= 1) {
            float xx = __shfl_up(pref, off, 64);
            if (t >= off) pref += xx;
        }
        float Eex = pref - p;
        int M = (int)__popcll(__ballot(Eex <= 0.9f));   // top-p kept prefix length

        int Mfinal;
        if (M >= K) {
            float kth = __shfl(v, K - 1, 64);
            int J = (int)__popcll(__ballot(v >= kth));  // kth-value tie-inclusive
            Mfinal = min(M, J);
        } else {
            Mfinal = M;                                  // kth == fmin, removes nothing
        }

        bool act = (t < Mfinal);
        float g  = act ? gumbel[base + (size_t)idx] : 0.f;
        float tt = act ? (v + g) : -FLT_MAX;
        int   ti = act ? idx : 0x7FFFFFFF;
        float bv = v;
        float bt = tt; int bi = ti;
        for (int off = 32; off > 0; off >>= 1) {
            float ot = __shfl_xor(bt, off, 64);
            int   oi = __shfl_xor(bi, off, 64);
            float ov = __shfl_xor(bv, off, 64);
            if (ot > bt || (ot == bt && oi < bi)) { bt = ot; bi = oi; bv = ov; }
        }
        float e = act ? expf(v - m0) : 0.f;
        float Z = e;
        for (int off = 32; off > 0; off >>= 1) Z += __shfl_xor(Z, off, 64);

        if (t == 0) {
            float conf = expf(bv - m0) / Z;   // softmax over filtered row at x0
            out[row] = conf;
            out[NROWS + row] = (float)bi;     // x0 as float value
            out[2 * NROWS + row] = conf;
        }
    }
}

extern "C" void kernel_launch(void* const* d_in, const int* in_sizes, int n_in,
                              void* d_out, int out_size, void* d_ws, size_t ws_size,
                              hipStream_t stream) {
    const float* logits = (const float*)d_in[0];
    const float* gumbel = (const float*)d_in[1];
    const int*   topk   = (const int*)d_in[2];
    float* out = (float*)d_out;
    sampler_kernel<<<NROWS, NTHREADS, 0, stream>>>(logits, gumbel, topk, out);
}

// Round 6
// 252.474 us; speedup vs baseline: 1.0990x; 1.0990x over previous
//
#include <hip/hip_runtime.h>
#include <cstdint>
#include <cfloat>
#include <math.h>

#define VCAB 128000
#define NROWS 256
#define NTH 1024
#define NBUCK 8192
#define CAP2 2560
#define CKN 1024

__device__ __forceinline__ unsigned mono(float f) {
    unsigned u = __float_as_uint(f);
    return (u & 0x80000000u) ? ~u : (u | 0x80000000u);
}
__device__ __forceinline__ float unmono(unsigned k) {
    return __uint_as_float((k & 0x80000000u) ? (k ^ 0x80000000u) : ~k);
}

// Wave 0 only (lanes 0..63). Scan hist downward from startb; return largest
// bucket b such that suffix-count(>= b) >= 64. Assumes total count >= 64.
__device__ __forceinline__ unsigned find_bstar_wave(const unsigned* hist, int startb, int lane) {
    int hb = startb;
    unsigned cum = 0u;
    for (int it = 0; it < 200; ++it) {
        int b = hb - lane;
        unsigned c = (b >= 0 && b < NBUCK) ? hist[b] : 0u;
        unsigned p = c;                         // inclusive prefix over lanes 0..lane
        #pragma unroll
        for (int off = 1; off < 64; off <<= 1) {
            unsigned q = __shfl_up(p, off, 64);
            if (lane >= off) p += q;
        }
        unsigned long long mm = __ballot(cum + p >= 64u);
        if (mm) {
            int l = __builtin_ctzll(mm);        // first crossing lane = highest bucket
            int b2 = hb - l;
            return (unsigned)(b2 > 0 ? b2 : 0);
        }
        cum += __shfl(p, 63, 64);
        hb -= 64;
        if (hb < 0) return 0u;
    }
    return 0u;
}

__global__ __launch_bounds__(NTH) void sampler_kernel(
    const float* __restrict__ logits,
    const float* __restrict__ gumbel,
    const int* __restrict__ topk_p,
    float* __restrict__ out)
{
    const int row = blockIdx.x;
    const int t = threadIdx.x;
    const size_t base = (size_t)row * VCAB;
    const float4* rowv = reinterpret_cast<const float4*>(logits + base);

    __shared__ unsigned hist[NBUCK];
    __shared__ unsigned long long cand[CAP2];
    __shared__ unsigned long long ck[CKN];
    __shared__ unsigned candCnt, candCnt2;
    __shared__ unsigned sh_bsamp, sh_bfin;
    __shared__ float red[16], red2[16];
    __shared__ float sh_msamp, sh_m0, sh_S;

    #pragma unroll
    for (int j = 0; j < NBUCK / NTH; ++j) hist[t + j * NTH] = 0u;
    if (t == 0) { candCnt = 0u; candCnt2 = 0u; }
    __syncthreads();

    // ---- sample pass: first 8192 elements (contiguous, coalesced) ----
    float smax = -FLT_MAX;
    #pragma unroll
    for (int ii = 0; ii < 2; ++ii) {
        float4 x = rowv[t + ii * NTH];
        float vs[4] = {x.x, x.y, x.z, x.w};
        #pragma unroll
        for (int c = 0; c < 4; ++c) {
            float v = vs[c];
            if (!(fabsf(v) <= FLT_MAX)) v = -FLT_MAX;   // sanitize NaN/±inf
            smax = fmaxf(smax, v);
            atomicAdd(&hist[mono(v) >> 19], 1u);
        }
    }
    for (int off = 32; off > 0; off >>= 1) smax = fmaxf(smax, __shfl_xor(smax, off, 64));
    if ((t & 63) == 0) red[t >> 6] = smax;
    __syncthreads();
    if (t < 16) {
        float m = red[t];
        #pragma unroll
        for (int off = 8; off > 0; off >>= 1) m = fmaxf(m, __shfl_xor(m, off, 16));
        if (t == 0) sh_msamp = m;
    }
    __syncthreads();
    const float msamp = sh_msamp;

    if (t < 64) {
        unsigned b = find_bstar_wave(hist, (int)(mono(msamp) >> 19), t);
        if (t == 0) sh_bsamp = b;
    }
    __syncthreads();
    // thrV = lower edge of bucket sh_bsamp:  {v >= thrV} == {bucket(v) >= sh_bsamp}
    const float thrV = unmono(sh_bsamp << 19);
    // re-zero hist for candidate-only histogram
    #pragma unroll
    for (int j = 0; j < NBUCK / NTH; ++j) hist[t + j * NTH] = 0u;
    __syncthreads();

    // ---- single main pass over the row ----
    float sacc[4] = {0.f, 0.f, 0.f, 0.f};
    float lacc[4] = {-FLT_MAX, -FLT_MAX, -FLT_MAX, -FLT_MAX};
    for (int i = t; i < VCAB / 4; i += NTH) {
        float4 x = rowv[i];
        float vs[4] = {x.x, x.y, x.z, x.w};
        #pragma unroll
        for (int c = 0; c < 4; ++c) {
            float v = vs[c];
            if (!(fabsf(v) <= FLT_MAX)) v = -FLT_MAX;
            lacc[c] = fmaxf(lacc[c], v);
            sacc[c] += __expf(v - msamp);
            if (v >= thrV) {                     // ~1.6% of elements
                unsigned k = mono(v);
                atomicAdd(&hist[k >> 19], 1u);
                unsigned pos = atomicAdd(&candCnt, 1u);
                if (pos < CAP2)
                    cand[pos] = ((unsigned long long)k << 32) |
                                (unsigned long long)(~(unsigned)(i * 4 + c));
            }
        }
    }
    float s = (sacc[0] + sacc[1]) + (sacc[2] + sacc[3]);
    float lmax = fmaxf(fmaxf(lacc[0], lacc[1]), fmaxf(lacc[2], lacc[3]));
    for (int off = 32; off > 0; off >>= 1) {
        lmax = fmaxf(lmax, __shfl_xor(lmax, off, 64));
        s += __shfl_xor(s, off, 64);
    }
    if ((t & 63) == 0) { red[t >> 6] = lmax; red2[t >> 6] = s; }
    __syncthreads();
    if (t < 16) {
        float m = red[t], z = red2[t];
        #pragma unroll
        for (int off = 8; off > 0; off >>= 1) {
            m = fmaxf(m, __shfl_xor(m, off, 16));
            z += __shfl_xor(z, off, 16);
        }
        if (t == 0) { sh_m0 = m; sh_S = z; }
    }
    __syncthreads();
    const float S = sh_S;

    // ---- exact final threshold bucket from candidate histogram ----
    if (t < 64) {
        unsigned b = find_bstar_wave(hist, (int)(mono(sh_m0) >> 19), t);
        if (t == 0) sh_bfin = b;
    }
    __syncthreads();
    const unsigned bfin = sh_bfin;

    ck[t] = 0ull;                                // pad: 0 sorts last descending
    __syncthreads();
    if (candCnt <= CAP2) {
        const unsigned nc = candCnt;
        for (unsigned j = t; j < nc; j += NTH) {
            unsigned long long e = cand[j];
            if ((unsigned)(e >> 51) >= bfin) {   // bucket of packed key
                unsigned pos = atomicAdd(&candCnt2, 1u);
                if (pos < CKN) ck[pos] = e;
            }
        }
    } else {
        // overflow fallback (≈ never): one L3-hot re-scan with the exact threshold
        const float thr2 = unmono(bfin << 19);
        for (int i = t; i < VCAB / 4; i += NTH) {
            float4 x = rowv[i];
            float vs[4] = {x.x, x.y, x.z, x.w};
            #pragma unroll
            for (int c = 0; c < 4; ++c) {
                float v = vs[c];
                if (!(fabsf(v) <= FLT_MAX)) v = -FLT_MAX;
                if (v >= thr2) {
                    unsigned pos = atomicAdd(&candCnt2, 1u);
                    if (pos < CKN)
                        ck[pos] = ((unsigned long long)mono(v) << 32) |
                                  (unsigned long long)(~(unsigned)(i * 4 + c));
                }
            }
        }
    }
    __syncthreads();

    // ---- bitonic sort, descending; 256-entry network when it fits ----
    const unsigned nc2 = candCnt2 < (unsigned)CKN ? candCnt2 : (unsigned)CKN;
    const int nsort = (nc2 <= 256u) ? 256 : CKN;
    for (int k = 2; k <= nsort; k <<= 1) {
        for (int j = k >> 1; j > 0; j >>= 1) {
            __syncthreads();
            if (t < nsort) {
                int l = t ^ j;
                if (l > t) {
                    unsigned long long a = ck[t], b = ck[l];
                    bool up = ((t & k) == 0);
                    if (up ? (a < b) : (a > b)) { ck[t] = b; ck[l] = a; }
                }
            }
        }
    }
    __syncthreads();

    // ---- epilogue: first wave on sorted top-64 ----
    if (t < 64) {
        unsigned long long key = ck[t];
        float v = unmono((unsigned)(key >> 32));
        int idx = (int)(~(unsigned)key);
        int K = *topk_p;
        K = min(max(K, 1), 64);

        // exclusive cumulative softmax prob (full-row S, base msamp — scale cancels)
        float p = expf(v - msamp) / S;
        float pref = p;
        for (int off = 1; off < 64; off <<= 1) {
            float xx = __shfl_up(pref, off, 64);
            if (t >= off) pref += xx;
        }
        float Eex = pref - p;
        int M = (int)__popcll(__ballot(Eex <= 0.9f));   // top-p kept prefix length

        int Mfinal;
        if (M >= K) {
            float kth = __shfl(v, K - 1, 64);
            int J = (int)__popcll(__ballot(v >= kth));  // kth-value tie-inclusive
            Mfinal = min(M, J);
        } else {
            Mfinal = M;
        }

        bool act = (t < Mfinal);
        float g  = act ? gumbel[base + (size_t)idx] : 0.f;
        float tt = act ? (v + g) : -FLT_MAX;
        int   ti = act ? idx : 0x7FFFFFFF;
        float bv = v;
        float bt = tt; int bi = ti;
        for (int off = 32; off > 0; off >>= 1) {
            float ot = __shfl_xor(bt, off, 64);
            int   oi = __shfl_xor(bi, off, 64);
            float ov = __shfl_xor(bv, off, 64);
            if (ot > bt || (ot == bt && oi < bi)) { bt = ot; bi = oi; bv = ov; }
        }
        float e = act ? expf(v - msamp) : 0.f;
        float Z = e;
        for (int off = 32; off > 0; off >>= 1) Z += __shfl_xor(Z, off, 64);

        if (t == 0) {
            float conf = expf(bv - msamp) / Z;  // softmax over filtered set at x0
            out[row] = conf;
            out[NROWS + row] = (float)bi;       // sampled index as float
            out[2 * NROWS + row] = conf;
        }
    }
}

extern "C" void kernel_launch(void* const* d_in, const int* in_sizes, int n_in,
                              void* d_out, int out_size, void* d_ws, size_t ws_size,
                              hipStream_t stream) {
    const float* logits = (const float*)d_in[0];
    const float* gumbel = (const float*)d_in[1];
    const int*   topk   = (const int*)d_in[2];
    float* out = (float*)d_out;
    sampler_kernel<<<NROWS, NTH, 0, stream>>>(logits, gumbel, topk, out);
}